// Round 9
// baseline (172.636 us; speedup 1.0000x reference)
//
#include <hip/hip_runtime.h>

#define S_  2048
#define D_  1024
#define H_  16
#define HD_ 64
#define M_  4096
#define K_  1024
#define NEL 4194304   // B*H*S*HD

typedef short  bf16x8 __attribute__((ext_vector_type(8)));
typedef float  f32x4  __attribute__((ext_vector_type(4)));
typedef float  f32x16 __attribute__((ext_vector_type(16)));
typedef unsigned int   u32;
typedef unsigned int   u32x4v __attribute__((ext_vector_type(4)));
typedef unsigned short u16;
typedef unsigned short u16x4 __attribute__((ext_vector_type(4)));

#define MFMA16(c,a,b) (c) = __builtin_amdgcn_mfma_f32_16x16x32_bf16((a),(b),(c),0,0,0)
#define MFMA32(c,a,b) (c) = __builtin_amdgcn_mfma_f32_32x32x16_bf16((a),(b),(c),0,0,0)

// Q pre-scale: 1/sqrt(64) * log2(e) -> softmax in exp2 domain
#define QSCALE 0.18033688011112042f

__device__ __forceinline__ u16 f2bf(float f) {
    union { float f; unsigned u; } v; v.f = f;
    unsigned u = v.u;
    u += 0x7FFFu + ((u >> 16) & 1u);   // RNE
    return (u16)(u >> 16);
}

__device__ __forceinline__ u32 cvtpk(float lo, float hi) {
    u32 r;
    asm("v_cvt_pk_bf16_f32 %0, %1, %2" : "=v"(r) : "v"(lo), "v"(hi));
    return r;
}

__device__ __forceinline__ void gload16(const void* g, void* l) {
    __builtin_amdgcn_global_load_lds(
        (const __attribute__((address_space(1))) unsigned*)g,
        (__attribute__((address_space(3))) unsigned*)l, 16, 0, 0);
}

// ---------------------------------------------------------------------------
__global__ __launch_bounds__(256) void cvt_x(const float* __restrict__ x,
                                             u16* __restrict__ xb) {
    const int i = (blockIdx.x * 256 + threadIdx.x) * 8;
    f32x4 a = *(const f32x4*)&x[i];
    f32x4 b = *(const f32x4*)&x[i + 4];
    u16 t[8];
#pragma unroll
    for (int j = 0; j < 4; ++j) { t[j] = f2bf(a[j]); t[4 + j] = f2bf(b[j]); }
    *(bf16x8*)&xb[i] = *(const bf16x8*)t;
}

// ---------------------------------------------------------------------------
__global__ __launch_bounds__(256) void cvt_w(const float* __restrict__ w0,
                                             const float* __restrict__ w1,
                                             const float* __restrict__ w2,
                                             const float* __restrict__ w3,
                                             u16* __restrict__ Wt) {
    __shared__ float T[64][65];
    const float* W = blockIdx.z == 0 ? w0 : blockIdx.z == 1 ? w1
                   : blockIdx.z == 2 ? w2 : w3;
    const int k0 = blockIdx.x * 64, n0 = blockIdx.y * 64;
    const int r  = threadIdx.x >> 2, c0 = (threadIdx.x & 3) * 16;
#pragma unroll
    for (int j = 0; j < 4; ++j)
        *(f32x4*)&T[r][c0 + j * 4] = *(const f32x4*)&W[(size_t)(k0 + r) * D_ + n0 + c0 + j * 4];
    __syncthreads();
    u16 tmp[16];
#pragma unroll
    for (int j = 0; j < 16; ++j) tmp[j] = f2bf(T[c0 + j][r]);
    u16* dst = Wt + ((size_t)blockIdx.z * 1024 + n0 + r) * K_ + k0 + c0;
    *(bf16x8*)dst       = *(const bf16x8*)tmp;
    *(bf16x8*)(dst + 8) = *(const bf16x8*)(tmp + 8);
}

// ---------------------------------------------------------------------------
// m97-style GEMM.  Biases passed directly; MODE 0 selects bq/bk/bv by n>>10.
// ---------------------------------------------------------------------------
template <int BM, int MODE>
__global__ __launch_bounds__(256) void gemm2(
    const u16* __restrict__ A, const u16* __restrict__ Bt,
    const float* __restrict__ b0, const float* __restrict__ b1,
    const float* __restrict__ b2, void* __restrict__ Out)
{
    __shared__ u16 As[BM * 32];
    __shared__ u16 Bs[128 * 32];
    const int tid = threadIdx.x, lane = tid & 63, wid = tid >> 6;
    const int lr = lane & 15, lg = lane >> 4;
    const int n0 = blockIdx.x * 128, m0 = blockIdx.y * BM;
    const int wm = (wid >> 1) * (BM / 2), wn = (wid & 1) * 64;
    const int lrow = lane >> 2, lch = lane & 3;

    f32x4 acc[BM / 32][4] = {};

    for (int k0 = 0; k0 < K_; k0 += 32) {
        __syncthreads();
#pragma unroll
        for (int t = 0; t < BM / 64; ++t) {
            const int row = wid * (BM / 4) + t * 16 + lrow;
            gload16(A + (size_t)(m0 + row) * K_ + k0 + lch * 8,
                    (u16*)As + row * 32 + lch * 8);
        }
#pragma unroll
        for (int t = 0; t < 2; ++t) {
            const int row = wid * 32 + t * 16 + lrow;
            gload16(Bt + (size_t)(n0 + row) * K_ + k0 + lch * 8,
                    (u16*)Bs + row * 32 + lch * 8);
        }
        __syncthreads();

        bf16x8 af[BM / 32], bf[4];
#pragma unroll
        for (int i = 0; i < BM / 32; ++i)
            af[i] = *(const bf16x8*)&As[(wm + i * 16 + lr) * 32 + lg * 8];
#pragma unroll
        for (int j = 0; j < 4; ++j)
            bf[j] = *(const bf16x8*)&Bs[(wn + j * 16 + lr) * 32 + lg * 8];
#pragma unroll
        for (int i = 0; i < BM / 32; ++i)
#pragma unroll
            for (int j = 0; j < 4; ++j) MFMA16(acc[i][j], af[i], bf[j]);
    }

#pragma unroll
    for (int i = 0; i < BM / 32; ++i) {
#pragma unroll
        for (int j = 0; j < 4; ++j) {
            const int n = n0 + wn + j * 16 + lr;
            const int m = m0 + wm + i * 16 + lg * 4;
            if constexpr (MODE == 0) {
                const int which = n >> 10, nn = n & 1023;
                const float* bp = which == 0 ? b0 : which == 1 ? b1 : b2;
                const float bv = bp[nn];
                u16* qkv = (u16*)Out;
                const int h = nn >> 6, hd = nn & 63;
                const int b = m >> 11, s = m & 2047;
                if (which == 2) {                         // V: [bh][hd][s]
                    u16x4 pk;
#pragma unroll
                    for (int r4 = 0; r4 < 4; ++r4) pk[r4] = f2bf(acc[i][j][r4] + bv);
                    *(u16x4*)&qkv[(size_t)2 * NEL +
                                  ((size_t)(b * H_ + h) * HD_ + hd) * S_ + s] = pk;
                } else {                                  // Q/K: [bh][s][hd]
                    const float sc = (which == 0) ? QSCALE : 1.0f;
                    const size_t bas = (size_t)which * NEL + (size_t)(b * H_ + h) * S_ * HD_;
#pragma unroll
                    for (int r4 = 0; r4 < 4; ++r4)
                        qkv[bas + (size_t)(s + r4) * HD_ + hd] =
                            f2bf((acc[i][j][r4] + bv) * sc);
                }
            } else {
                const float bv = b0[n];
                float* o = (float*)Out;
#pragma unroll
                for (int r4 = 0; r4 < 4; ++r4)
                    o[(size_t)(m + r4) * D_ + n] = acc[i][j][r4] + bv;
            }
        }
    }
}

// ---------------------------------------------------------------------------
// attn8: swapped-QK^T flash + KV-split x4 + causal pairing, restructured to
// process ONE 32-kv subtile at a time to cut register footprint:
//   round 8: cT[2](32) + pk[2][8](16) + vf[2][4](32) live across softmax
//            -> arch 124 + acc 64 = 188 total -> 2 waves/SIMD (the 84us wall)
//   now:     cT(16) + pk[8](8) + vf loaded just before PV
//            -> target <=128 total -> 4 waves/SIMD (>=3 floored by
//            __launch_bounds__(256,3), budget 170, spill-free)
// Pointer-increment addressing replaces per-pass 64-bit address recompute.
// Datapath math identical to rounds 4-8 (verified absmax 0.015625).
// C/D layout: col=lane&31, row=(r&3)+8(r>>2)+4*(lane>>5)  [m74/m101].
// ---------------------------------------------------------------------------
__global__ __launch_bounds__(256, 3) void attn8(
    const u16* __restrict__ Q, const u16* __restrict__ K,
    const u16* __restrict__ Vt, u16* __restrict__ CTX)
{
    __shared__ float OB[2][64][33];   // partial O, pad 33 -> conflict-free
    __shared__ float MB[2][64], LB[2][64];

    const int tid  = threadIdx.x;
    const int lane = tid & 63, wv = tid >> 6;
    const int lo = lane & 31, hi = lane >> 5;
    const int idx = blockIdx.x;
    const int bh  = idx & 31;
    const int pu  = idx >> 5;              // pair index 0..31
    const size_t base  = (size_t)bh * S_ * HD_;   // Q,K: [bh][s][hd]
    const size_t vbase = (size_t)bh * HD_ * S_;   // Vt:  [bh][hd][s]
    const int b = bh >> 4, h = bh & 15;

    for (int mem = 0; mem < 2; ++mem) {
        const int qb  = mem == 0 ? 63 - pu : pu;
        const int wq0 = qb * 32;

        // Q as B-fragment: lane holds col q=lo, k = 16*ks + 8*hi + j
        bf16x8 qf[4];
#pragma unroll
        for (int ks = 0; ks < 4; ++ks)
            qf[ks] = *(const bf16x8*)&Q[base + (size_t)(wq0 + lo) * HD_ + ks * 16 + hi * 8];

        f32x16 acc[2] = {};
        float m_ = -1e30f, l_ = 0.f;
        const int nt = (wq0 >> 6) + 1;

        // per-lane base pointers, advanced by += (4 tiles) per iteration
        const u16* kRow  = K  + base  + (size_t)(wv * 64 + lo) * HD_ + hi * 8;
        const u16* vRow0 = Vt + vbase + (size_t)lo * S_        + wv * 64 + hi * 8;
        const u16* vRow1 = Vt + vbase + (size_t)(32 + lo) * S_ + wv * 64 + hi * 8;

        for (int t = wv; t < nt; t += 4) {
            const int kv0 = t * 64;
            const int nsub = (kv0 + 32 <= wq0 + 31) ? 2 : 1;

            for (int sub = 0; sub < nsub; ++sub) {
                const int so = sub * 32;   // subtile kv offset

                // ---- QK^T (S^T) for 32 kv: A = K rows, B = Q ----
                f32x16 cT = {};
                __builtin_amdgcn_s_setprio(1);
#pragma unroll
                for (int ks = 0; ks < 4; ++ks) {
                    bf16x8 kf = *(const bf16x8*)(kRow + so * HD_ + ks * 16);
                    MFMA32(cT, kf, qf[ks]);
                }
                __builtin_amdgcn_s_setprio(0);

                // ---- causal mask (diagonal subtiles only) ----
                if (kv0 + so + 31 > wq0) {
                    const int qg = wq0 + lo;
#pragma unroll
                    for (int r = 0; r < 16; ++r) {
                        const int kvg = kv0 + so + (r & 3) + 8 * (r >> 2) + 4 * hi;
                        if (kvg > qg) cT[r] = -1e9f;
                    }
                }

                // ---- row max over 32 kv: 15 fmax + 1 cross-lane ----
                float t8[8];
#pragma unroll
                for (int i = 0; i < 8; ++i) t8[i] = fmaxf(cT[i], cT[i + 8]);
                float mx = fmaxf(fmaxf(fmaxf(t8[0], t8[1]), fmaxf(t8[2], t8[3])),
                                 fmaxf(fmaxf(t8[4], t8[5]), fmaxf(t8[6], t8[7])));
                mx = fmaxf(mx, __shfl_xor(mx, 32));

                // ---- defer-max (T13, exp2 domain: 11.5 = 8*log2e) ----
                if (!__all(mx <= m_ + 11.5f)) {
                    const float mn = fmaxf(m_, mx);
                    const float al = exp2f(m_ - mn);
                    m_ = mn; l_ *= al;
                    float alr[16];
#pragma unroll
                    for (int r = 0; r < 16; ++r)
                        alr[r] = __shfl(al, (r & 3) + 8 * (r >> 2) + 4 * hi);
#pragma unroll
                    for (int r = 0; r < 16; ++r) { acc[0][r] *= alr[r]; acc[1][r] *= alr[r]; }
                }

                // ---- P = exp2(S - m), lane-local sum + 1 cross-lane ----
#pragma unroll
                for (int i = 0; i < 16; ++i) cT[i] = exp2f(cT[i] - m_);
#pragma unroll
                for (int i = 0; i < 8; ++i) t8[i] = cT[i] + cT[i + 8];
                float ssum = ((t8[0] + t8[1]) + (t8[2] + t8[3])) +
                             ((t8[4] + t8[5]) + (t8[6] + t8[7]));
                ssum += __shfl_xor(ssum, 32);
                l_ += ssum;

                // ---- pack P to bf16 pairs ----
                u32 pk[8];
#pragma unroll
                for (int w = 0; w < 8; ++w)
                    pk[w] = cvtpk(cT[2 * w], cT[2 * w + 1]);

                // ---- V loads issued now (af build hides latency) ----
                bf16x8 vf00 = *(const bf16x8*)(vRow0 + so);
                bf16x8 vf10 = *(const bf16x8*)(vRow1 + so);
                bf16x8 vf01 = *(const bf16x8*)(vRow0 + so + 16);
                bf16x8 vf11 = *(const bf16x8*)(vRow1 + so + 16);

                // ---- A-frags (verified construction, per subtile) ----
                bf16x8 af0, af1;
                {   // ks2 = 0: ma=0, mb=1
                    const u32 own0 = hi ? pk[2] : pk[0];
                    const u32 own1 = hi ? pk[3] : pk[1];
                    const u32 snd0 = hi ? pk[0] : pk[2];
                    const u32 snd1 = hi ? pk[1] : pk[3];
                    const u32 rcv0 = (u32)__shfl_xor((int)snd0, 32);
                    const u32 rcv1 = (u32)__shfl_xor((int)snd1, 32);
                    u32x4v v;
                    v.x = hi ? rcv0 : own0;  v.y = hi ? rcv1 : own1;
                    v.z = hi ? own0 : rcv0;  v.w = hi ? own1 : rcv1;
                    af0 = __builtin_bit_cast(bf16x8, v);
                }
                {   // ks2 = 1: ma=2, mb=3
                    const u32 own0 = hi ? pk[6] : pk[4];
                    const u32 own1 = hi ? pk[7] : pk[5];
                    const u32 snd0 = hi ? pk[4] : pk[6];
                    const u32 snd1 = hi ? pk[5] : pk[7];
                    const u32 rcv0 = (u32)__shfl_xor((int)snd0, 32);
                    const u32 rcv1 = (u32)__shfl_xor((int)snd1, 32);
                    u32x4v v;
                    v.x = hi ? rcv0 : own0;  v.y = hi ? rcv1 : own1;
                    v.z = hi ? own0 : rcv0;  v.w = hi ? own1 : rcv1;
                    af1 = __builtin_bit_cast(bf16x8, v);
                }

                // ---- PV ----
                __builtin_amdgcn_s_setprio(1);
                MFMA32(acc[0], af0, vf00);
                MFMA32(acc[1], af0, vf10);
                MFMA32(acc[0], af1, vf01);
                MFMA32(acc[1], af1, vf11);
                __builtin_amdgcn_s_setprio(0);
            }

            kRow  += 256 * HD_;
            vRow0 += 256;
            vRow1 += 256;
        }

        // ---- 2-stage merge tree (all waves participate in barriers) ----
        if (wv >= 2) {
            const int bb = wv - 2;
#pragma unroll
            for (int r = 0; r < 16; ++r) {
                OB[bb][lane][r]      = acc[0][r];
                OB[bb][lane][16 + r] = acc[1][r];
            }
            MB[bb][lane] = m_;
            LB[bb][lane] = l_;
        }
        __syncthreads();
        if (wv < 2) {   // w0 += buf0, w1 += buf1
            const int bb = wv;
            const float m1 = MB[bb][lane], l1 = LB[bb][lane];
            const float mM = fmaxf(m_, m1);
            const float a0 = exp2f(m_ - mM), a1 = exp2f(m1 - mM);
            m_ = mM;
            l_ = l_ * a0 + l1 * a1;
            float a0r[16], a1r[16];
#pragma unroll
            for (int r = 0; r < 16; ++r) {
                const int rq = (r & 3) + 8 * (r >> 2) + 4 * hi;
                a0r[r] = __shfl(a0, rq);
                a1r[r] = __shfl(a1, rq);
            }
#pragma unroll
            for (int r = 0; r < 16; ++r) {
                acc[0][r] = acc[0][r] * a0r[r] + OB[bb][lane][r]      * a1r[r];
                acc[1][r] = acc[1][r] * a0r[r] + OB[bb][lane][16 + r] * a1r[r];
            }
        }
        __syncthreads();
        if (wv == 1) {  // stage B: w1 -> buf0
#pragma unroll
            for (int r = 0; r < 16; ++r) {
                OB[0][lane][r]      = acc[0][r];
                OB[0][lane][16 + r] = acc[1][r];
            }
            MB[0][lane] = m_;
            LB[0][lane] = l_;
        }
        __syncthreads();
        if (wv == 0) {  // w0 += buf0, normalize, store
            const float m1 = MB[0][lane], l1 = LB[0][lane];
            const float mM = fmaxf(m_, m1);
            const float a0 = exp2f(m_ - mM), a1 = exp2f(m1 - mM);
            l_ = l_ * a0 + l1 * a1;
            float a0r[16], a1r[16];
#pragma unroll
            for (int r = 0; r < 16; ++r) {
                const int rq = (r & 3) + 8 * (r >> 2) + 4 * hi;
                a0r[r] = __shfl(a0, rq);
                a1r[r] = __shfl(a1, rq);
            }
#pragma unroll
            for (int r = 0; r < 16; ++r) {
                acc[0][r] = acc[0][r] * a0r[r] + OB[0][lane][r]      * a1r[r];
                acc[1][r] = acc[1][r] * a0r[r] + OB[0][lane][16 + r] * a1r[r];
            }

            const float linv = 1.0f / l_;
            float lrr[16];
#pragma unroll
            for (int r = 0; r < 16; ++r)
                lrr[r] = __shfl(linv, (r & 3) + 8 * (r >> 2) + 4 * hi);
#pragma unroll
            for (int r = 0; r < 16; ++r) {
                const int q = wq0 + (r & 3) + 8 * (r >> 2) + 4 * hi;
                u16* o = &CTX[(size_t)(b * S_ + q) * D_ + h * HD_ + lo];
                o[0]  = f2bf(acc[0][r] * lrr[r]);
                o[32] = f2bf(acc[1][r] * lrr[r]);
            }
        }
        __syncthreads();   // OB/MB/LB safe to reuse for next member
    }
}

// ---------------------------------------------------------------------------
extern "C" void kernel_launch(void* const* d_in, const int* in_sizes, int n_in,
                              void* d_out, int out_size, void* d_ws, size_t ws_size,
                              hipStream_t stream)
{
    const float* x  = (const float*)d_in[0];
    const float* wq = (const float*)d_in[1];
    const float* bq = (const float*)d_in[2];
    const float* wk = (const float*)d_in[3];
    const float* bk = (const float*)d_in[4];
    const float* wv = (const float*)d_in[5];
    const float* bv = (const float*)d_in[6];
    const float* wo = (const float*)d_in[7];
    const float* bo = (const float*)d_in[8];

    char* ws = (char*)d_ws;
    u16*   xb    = (u16*)ws;                                  // 8 MB (reused as ctx)
    u16*   WtAll = (u16*)(ws + (size_t)8  * 1024 * 1024);     // 8 MB, rows q|k|v|o
    u16*   qkv   = (u16*)(ws + (size_t)16 * 1024 * 1024);     // 24 MB: q | k | vT
    u16*   ctx   = xb;

    cvt_x<<<2048, 256, 0, stream>>>(x, xb);
    cvt_w<<<dim3(16, 16, 4), 256, 0, stream>>>(wq, wk, wv, wo, WtAll);

    gemm2<128, 0><<<dim3(24, 32), 256, 0, stream>>>(xb, WtAll, bq, bk, bv, qkv);

    attn8<<<dim3(1024), 256, 0, stream>>>(qkv, qkv + NEL, qkv + 2 * (size_t)NEL, ctx);

    gemm2<64, 1><<<dim3(8, 64), 256, 0, stream>>>(ctx, WtAll + (size_t)3072 * K_,
                                                  bo, bo, bo, d_out);
}

// Round 12
// 149.600 us; speedup vs baseline: 1.1540x; 1.1540x over previous
//
#include <hip/hip_runtime.h>

#define S_  2048
#define D_  1024
#define H_  16
#define HD_ 64
#define M_  4096
#define K_  1024
#define NEL 4194304   // B*H*S*HD

typedef short  bf16x8 __attribute__((ext_vector_type(8)));
typedef float  f32x4  __attribute__((ext_vector_type(4)));
typedef float  f32x16 __attribute__((ext_vector_type(16)));
typedef unsigned int   u32;
typedef unsigned int   u32x4v __attribute__((ext_vector_type(4)));
typedef unsigned short u16;
typedef unsigned short u16x4 __attribute__((ext_vector_type(4)));

#define MFMA16(c,a,b) (c) = __builtin_amdgcn_mfma_f32_16x16x32_bf16((a),(b),(c),0,0,0)
#define MFMA32(c,a,b) (c) = __builtin_amdgcn_mfma_f32_32x32x16_bf16((a),(b),(c),0,0,0)

// Q pre-scale: 1/sqrt(64) * log2(e) -> softmax in exp2 domain
#define QSCALE 0.18033688011112042f

__device__ __forceinline__ u16 f2bf(float f) {
    union { float f; unsigned u; } v; v.f = f;
    unsigned u = v.u;
    u += 0x7FFFu + ((u >> 16) & 1u);   // RNE
    return (u16)(u >> 16);
}

__device__ __forceinline__ u32 cvtpk(float lo, float hi) {
    u32 r;
    asm("v_cvt_pk_bf16_f32 %0, %1, %2" : "=v"(r) : "v"(lo), "v"(hi));
    return r;
}

__device__ __forceinline__ void gload16(const void* g, void* l) {
    __builtin_amdgcn_global_load_lds(
        (const __attribute__((address_space(1))) unsigned*)g,
        (__attribute__((address_space(3))) unsigned*)l, 16, 0, 0);
}

// ---------------------------------------------------------------------------
__global__ __launch_bounds__(256) void cvt_x(const float* __restrict__ x,
                                             u16* __restrict__ xb) {
    const int i = (blockIdx.x * 256 + threadIdx.x) * 8;
    f32x4 a = *(const f32x4*)&x[i];
    f32x4 b = *(const f32x4*)&x[i + 4];
    u16 t[8];
#pragma unroll
    for (int j = 0; j < 4; ++j) { t[j] = f2bf(a[j]); t[4 + j] = f2bf(b[j]); }
    *(bf16x8*)&xb[i] = *(const bf16x8*)t;
}

// ---------------------------------------------------------------------------
__global__ __launch_bounds__(256) void cvt_w(const float* __restrict__ w0,
                                             const float* __restrict__ w1,
                                             const float* __restrict__ w2,
                                             const float* __restrict__ w3,
                                             u16* __restrict__ Wt) {
    __shared__ float T[64][65];
    const float* W = blockIdx.z == 0 ? w0 : blockIdx.z == 1 ? w1
                   : blockIdx.z == 2 ? w2 : w3;
    const int k0 = blockIdx.x * 64, n0 = blockIdx.y * 64;
    const int r  = threadIdx.x >> 2, c0 = (threadIdx.x & 3) * 16;
#pragma unroll
    for (int j = 0; j < 4; ++j)
        *(f32x4*)&T[r][c0 + j * 4] = *(const f32x4*)&W[(size_t)(k0 + r) * D_ + n0 + c0 + j * 4];
    __syncthreads();
    u16 tmp[16];
#pragma unroll
    for (int j = 0; j < 16; ++j) tmp[j] = f2bf(T[c0 + j][r]);
    u16* dst = Wt + ((size_t)blockIdx.z * 1024 + n0 + r) * K_ + k0 + c0;
    *(bf16x8*)dst       = *(const bf16x8*)tmp;
    *(bf16x8*)(dst + 8) = *(const bf16x8*)(tmp + 8);
}

// ---------------------------------------------------------------------------
// m97-style GEMM.  Biases passed directly; MODE 0 selects bq/bk/bv by n>>10
// (proven rounds 6-9).
// ---------------------------------------------------------------------------
template <int BM, int MODE>
__global__ __launch_bounds__(256) void gemm2(
    const u16* __restrict__ A, const u16* __restrict__ Bt,
    const float* __restrict__ b0, const float* __restrict__ b1,
    const float* __restrict__ b2, void* __restrict__ Out)
{
    __shared__ u16 As[BM * 32];
    __shared__ u16 Bs[128 * 32];
    const int tid = threadIdx.x, lane = tid & 63, wid = tid >> 6;
    const int lr = lane & 15, lg = lane >> 4;
    const int n0 = blockIdx.x * 128, m0 = blockIdx.y * BM;
    const int wm = (wid >> 1) * (BM / 2), wn = (wid & 1) * 64;
    const int lrow = lane >> 2, lch = lane & 3;

    f32x4 acc[BM / 32][4] = {};

    for (int k0 = 0; k0 < K_; k0 += 32) {
        __syncthreads();
#pragma unroll
        for (int t = 0; t < BM / 64; ++t) {
            const int row = wid * (BM / 4) + t * 16 + lrow;
            gload16(A + (size_t)(m0 + row) * K_ + k0 + lch * 8,
                    (u16*)As + row * 32 + lch * 8);
        }
#pragma unroll
        for (int t = 0; t < 2; ++t) {
            const int row = wid * 32 + t * 16 + lrow;
            gload16(Bt + (size_t)(n0 + row) * K_ + k0 + lch * 8,
                    (u16*)Bs + row * 32 + lch * 8);
        }
        __syncthreads();

        bf16x8 af[BM / 32], bf[4];
#pragma unroll
        for (int i = 0; i < BM / 32; ++i)
            af[i] = *(const bf16x8*)&As[(wm + i * 16 + lr) * 32 + lg * 8];
#pragma unroll
        for (int j = 0; j < 4; ++j)
            bf[j] = *(const bf16x8*)&Bs[(wn + j * 16 + lr) * 32 + lg * 8];
#pragma unroll
        for (int i = 0; i < BM / 32; ++i)
#pragma unroll
            for (int j = 0; j < 4; ++j) MFMA16(acc[i][j], af[i], bf[j]);
    }

#pragma unroll
    for (int i = 0; i < BM / 32; ++i) {
#pragma unroll
        for (int j = 0; j < 4; ++j) {
            const int n = n0 + wn + j * 16 + lr;
            const int m = m0 + wm + i * 16 + lg * 4;
            if constexpr (MODE == 0) {
                const int which = n >> 10, nn = n & 1023;
                const float* bp = which == 0 ? b0 : which == 1 ? b1 : b2;
                const float bv = bp[nn];
                u16* qkv = (u16*)Out;
                const int h = nn >> 6, hd = nn & 63;
                const int b = m >> 11, s = m & 2047;
                if (which == 2) {                         // V: [bh][hd][s]
                    u16x4 pk;
#pragma unroll
                    for (int r4 = 0; r4 < 4; ++r4) pk[r4] = f2bf(acc[i][j][r4] + bv);
                    *(u16x4*)&qkv[(size_t)2 * NEL +
                                  ((size_t)(b * H_ + h) * HD_ + hd) * S_ + s] = pk;
                } else {                                  // Q/K: [bh][s][hd]
                    const float sc = (which == 0) ? QSCALE : 1.0f;
                    const size_t bas = (size_t)which * NEL + (size_t)(b * H_ + h) * S_ * HD_;
#pragma unroll
                    for (int r4 = 0; r4 < 4; ++r4)
                        qkv[bas + (size_t)(s + r4) * HD_ + hd] =
                            f2bf((acc[i][j][r4] + bv) * sc);
                }
            } else {
                const float bv = b0[n];
                float* o = (float*)Out;
#pragma unroll
                for (int r4 = 0; r4 < 4; ++r4)
                    o[(size_t)(m + r4) * D_ + n] = acc[i][j][r4] + bv;
            }
        }
    }
}

// ---------------------------------------------------------------------------
// attn5 (round-5 verbatim — best measured passing attn: 73us).  Swapped-QK^T
// flash + KV-split x2.  Block = 2 waves, one (bh, 32-row q-block); wave w
// handles kv tiles t = w, w+2, ...; in-block merge via LDS.
// A-frags built with the MACHINE-VERIFIED select+__shfl_xor construction
// (permlane variants failed twice: rounds 10/11 — abandoned).
// C/D layout: col=lane&31, row=(r&3)+8(r>>2)+4*(lane>>5)  [m74/m101].
// ---------------------------------------------------------------------------
__global__ __launch_bounds__(128) void attn5(
    const u16* __restrict__ Q, const u16* __restrict__ K,
    const u16* __restrict__ Vt, u16* __restrict__ CTX)
{
    __shared__ float OB[64][33];   // wave1 partial O (r-space), pad -> conflict-free
    __shared__ float MB[64], LB[64];

    const int tid  = threadIdx.x;
    const int lane = tid & 63, wv = tid >> 6;
    const int lo = lane & 31, hi = lane >> 5;
    const int idx = blockIdx.x;
    const int bh  = idx & 31;
    const int qb  = 63 - (idx >> 5);       // heavy q-blocks first
    const int wq0 = qb * 32;
    const size_t base  = (size_t)bh * S_ * HD_;   // Q,K: [bh][s][hd]
    const size_t vbase = (size_t)bh * HD_ * S_;   // Vt:  [bh][hd][s]

    // Q as B-fragment: lane holds col q=lo, k = 16*ks + 8*hi + j
    bf16x8 qf[4];
#pragma unroll
    for (int ks = 0; ks < 4; ++ks)
        qf[ks] = *(const bf16x8*)&Q[base + (size_t)(wq0 + lo) * HD_ + ks * 16 + hi * 8];

    f32x16 acc[2] = {};
    float m_ = -1e30f, l_ = 0.f;
    const int nt = (wq0 >> 6) + 1;

    for (int t = wv; t < nt; t += 2) {
        const int kv0 = t * 64;
        const bool sub1 = (kv0 + 32 <= wq0 + 31);

        // ---- QK^T (S^T): A = K rows, B = Q ----
        f32x16 cT[2];
#pragma unroll
        for (int i = 0; i < 16; ++i) { cT[0][i] = 0.f; cT[1][i] = 0.f; }
        __builtin_amdgcn_s_setprio(1);
#pragma unroll
        for (int ks = 0; ks < 4; ++ks) {
            bf16x8 kf = *(const bf16x8*)&K[base + (size_t)(kv0 + lo) * HD_ + ks * 16 + hi * 8];
            MFMA32(cT[0], kf, qf[ks]);
        }
        if (sub1) {
#pragma unroll
            for (int ks = 0; ks < 4; ++ks) {
                bf16x8 kf = *(const bf16x8*)&K[base + (size_t)(kv0 + 32 + lo) * HD_ + ks * 16 + hi * 8];
                MFMA32(cT[1], kf, qf[ks]);
            }
        }
        __builtin_amdgcn_s_setprio(0);

        // ---- V B-frags issued early (hide under softmax) ----
        bf16x8 vf[2][4];
#pragma unroll
        for (int dt = 0; dt < 2; ++dt)
#pragma unroll
            for (int ks = 0; ks < 4; ++ks)
                if (ks < 2 || sub1)
                    vf[dt][ks] = *(const bf16x8*)&Vt[vbase + (size_t)(dt * 32 + lo) * S_ +
                                                     kv0 + ks * 16 + hi * 8];

        // ---- causal mask (diagonal passes only) ----
        if (kv0 + 63 > wq0) {
            const int qg = wq0 + lo;
#pragma unroll
            for (int tt = 0; tt < 2; ++tt)
#pragma unroll
                for (int r = 0; r < 16; ++r) {
                    const int kvg = kv0 + tt * 32 + (r & 3) + 8 * (r >> 2) + 4 * hi;
                    if (kvg > qg) cT[tt][r] = -1e9f;
                }
        }

        // ---- row max: in-register tree + 1 cross-lane ----
        float m8[8];
#pragma unroll
        for (int i = 0; i < 8; ++i)
            m8[i] = fmaxf(fmaxf(cT[0][i], cT[0][i + 8]), fmaxf(cT[1][i], cT[1][i + 8]));
        float mx = fmaxf(fmaxf(fmaxf(m8[0], m8[1]), fmaxf(m8[2], m8[3])),
                         fmaxf(fmaxf(m8[4], m8[5]), fmaxf(m8[6], m8[7])));
        mx = fmaxf(mx, __shfl_xor(mx, 32));

        // ---- defer-max (T13, exp2 domain: 11.5 = 8*log2e) ----
        if (!__all(mx <= m_ + 11.5f)) {
            const float mn = fmaxf(m_, mx);
            const float al = exp2f(m_ - mn);
            m_ = mn; l_ *= al;
            float alr[16];
#pragma unroll
            for (int r = 0; r < 16; ++r)
                alr[r] = __shfl(al, (r & 3) + 8 * (r >> 2) + 4 * hi);
#pragma unroll
            for (int r = 0; r < 16; ++r) { acc[0][r] *= alr[r]; acc[1][r] *= alr[r]; }
        }

        // ---- P = exp2(S - m), lane-local sum + 1 cross-lane ----
#pragma unroll
        for (int i = 0; i < 16; ++i) {
            cT[0][i] = exp2f(cT[0][i] - m_);
            cT[1][i] = exp2f(cT[1][i] - m_);
        }
        float s8[8];
#pragma unroll
        for (int i = 0; i < 8; ++i)
            s8[i] = (cT[0][i] + cT[0][i + 8]) + (cT[1][i] + cT[1][i + 8]);
        float ssum = ((s8[0] + s8[1]) + (s8[2] + s8[3])) +
                     ((s8[4] + s8[5]) + (s8[6] + s8[7]));
        ssum += __shfl_xor(ssum, 32);
        l_ += ssum;

        // ---- pack P to bf16 pairs ----
        u32 pk[2][8];
#pragma unroll
        for (int tt = 0; tt < 2; ++tt)
#pragma unroll
            for (int w = 0; w < 8; ++w)
                pk[tt][w] = cvtpk(cT[tt][2 * w], cT[tt][2 * w + 1]);

        // ---- build PV A-frags in registers; PV ----
#pragma unroll
        for (int ks = 0; ks < 4; ++ks) {
            if (ks < 2 || sub1) {
                const int tt = ks >> 1;
                const int ma = (2 * ks) & 3;
                const int mb = (2 * ks + 1) & 3;
                const u32 own0 = hi ? pk[tt][2 * mb]     : pk[tt][2 * ma];
                const u32 own1 = hi ? pk[tt][2 * mb + 1] : pk[tt][2 * ma + 1];
                const u32 snd0 = hi ? pk[tt][2 * ma]     : pk[tt][2 * mb];
                const u32 snd1 = hi ? pk[tt][2 * ma + 1] : pk[tt][2 * mb + 1];
                const u32 rcv0 = (u32)__shfl_xor((int)snd0, 32);
                const u32 rcv1 = (u32)__shfl_xor((int)snd1, 32);
                u32x4v afv;
                afv.x = hi ? rcv0 : own0;
                afv.y = hi ? rcv1 : own1;
                afv.z = hi ? own0 : rcv0;
                afv.w = hi ? own1 : rcv1;
                const bf16x8 af = __builtin_bit_cast(bf16x8, afv);
                __builtin_amdgcn_s_setprio(1);
                MFMA32(acc[0], af, vf[0][ks]);
                MFMA32(acc[1], af, vf[1][ks]);
                __builtin_amdgcn_s_setprio(0);
            }
        }
    }

    // ---- in-block merge: wave1 publishes, wave0 combines + stores ----
    if (wv == 1) {
#pragma unroll
        for (int r = 0; r < 16; ++r) {
            OB[lane][r]      = acc[0][r];
            OB[lane][16 + r] = acc[1][r];
        }
        MB[lane] = m_;
        LB[lane] = l_;
    }
    __syncthreads();
    if (wv != 0) return;

    const float m1 = MB[lane], l1 = LB[lane];
    const float mM = fmaxf(m_, m1);
    const float a0 = exp2f(m_ - mM), a1 = exp2f(m1 - mM);
    l_ = l_ * a0 + l1 * a1;
    float a0r[16], a1r[16];
#pragma unroll
    for (int r = 0; r < 16; ++r) {
        const int rq = (r & 3) + 8 * (r >> 2) + 4 * hi;
        a0r[r] = __shfl(a0, rq);
        a1r[r] = __shfl(a1, rq);
    }
#pragma unroll
    for (int r = 0; r < 16; ++r) {
        acc[0][r] = acc[0][r] * a0r[r] + OB[lane][r]      * a1r[r];
        acc[1][r] = acc[1][r] * a0r[r] + OB[lane][16 + r] * a1r[r];
    }

    const float linv = 1.0f / l_;
    float lrr[16];
#pragma unroll
    for (int r = 0; r < 16; ++r)
        lrr[r] = __shfl(linv, (r & 3) + 8 * (r >> 2) + 4 * hi);
    const int b = bh >> 4, h = bh & 15;
#pragma unroll
    for (int r = 0; r < 16; ++r) {
        const int q = wq0 + (r & 3) + 8 * (r >> 2) + 4 * hi;
        u16* o = &CTX[(size_t)(b * S_ + q) * D_ + h * HD_ + lo];
        o[0]  = f2bf(acc[0][r] * lrr[r]);
        o[32] = f2bf(acc[1][r] * lrr[r]);
    }
}

// ---------------------------------------------------------------------------
extern "C" void kernel_launch(void* const* d_in, const int* in_sizes, int n_in,
                              void* d_out, int out_size, void* d_ws, size_t ws_size,
                              hipStream_t stream)
{
    const float* x  = (const float*)d_in[0];
    const float* wq = (const float*)d_in[1];
    const float* bq = (const float*)d_in[2];
    const float* wk = (const float*)d_in[3];
    const float* bk = (const float*)d_in[4];
    const float* wv = (const float*)d_in[5];
    const float* bv = (const float*)d_in[6];
    const float* wo = (const float*)d_in[7];
    const float* bo = (const float*)d_in[8];

    char* ws = (char*)d_ws;
    u16*   xb    = (u16*)ws;                                  // 8 MB (reused as ctx)
    u16*   WtAll = (u16*)(ws + (size_t)8  * 1024 * 1024);     // 8 MB, rows q|k|v|o
    u16*   qkv   = (u16*)(ws + (size_t)16 * 1024 * 1024);     // 24 MB: q | k | vT
    u16*   ctx   = xb;

    cvt_x<<<2048, 256, 0, stream>>>(x, xb);
    cvt_w<<<dim3(16, 16, 4), 256, 0, stream>>>(wq, wk, wv, wo, WtAll);

    gemm2<128, 0><<<dim3(24, 32), 256, 0, stream>>>(xb, WtAll, bq, bk, bv, qkv);

    attn5<<<dim3(2048), 128, 0, stream>>>(qkv, qkv + NEL, qkv + 2 * (size_t)NEL, ctx);

    gemm2<64, 1><<<dim3(8, 64), 256, 0, stream>>>(ctx, WtAll + (size_t)3072 * K_,
                                                  bo, bo, bo, d_out);
}

// Round 13
// 149.335 us; speedup vs baseline: 1.1560x; 1.0018x over previous
//
#include <hip/hip_runtime.h>

#define S_  2048
#define D_  1024
#define H_  16
#define HD_ 64
#define M_  4096
#define K_  1024
#define NEL 4194304   // B*H*S*HD

typedef short  bf16x8 __attribute__((ext_vector_type(8)));
typedef float  f32x4  __attribute__((ext_vector_type(4)));
typedef float  f32x16 __attribute__((ext_vector_type(16)));
typedef unsigned int   u32;
typedef unsigned int   u32x2 __attribute__((ext_vector_type(2)));
typedef unsigned int   u32x4v __attribute__((ext_vector_type(4)));
typedef unsigned short u16;
typedef unsigned short u16x4 __attribute__((ext_vector_type(4)));

#define MFMA16(c,a,b) (c) = __builtin_amdgcn_mfma_f32_16x16x32_bf16((a),(b),(c),0,0,0)
#define MFMA32(c,a,b) (c) = __builtin_amdgcn_mfma_f32_32x32x16_bf16((a),(b),(c),0,0,0)

// Q pre-scale: 1/sqrt(64) * log2(e) -> softmax in exp2 domain
#define QSCALE 0.18033688011112042f

__device__ __forceinline__ u16 f2bf(float f) {
    union { float f; unsigned u; } v; v.f = f;
    unsigned u = v.u;
    u += 0x7FFFu + ((u >> 16) & 1u);   // RNE
    return (u16)(u >> 16);
}

__device__ __forceinline__ u32 cvtpk(float lo, float hi) {
    u32 r;
    asm("v_cvt_pk_bf16_f32 %0, %1, %2" : "=v"(r) : "v"(lo), "v"(hi));
    return r;
}

// permlane32_swap: vdst_row1 <-> src0_row0.  Returns {vdst', vsrc'} (LLVM
// doc order).  ROUND-11 LESSON: never call with aliased operands (plswap2(u,u)
// coalesces -> in-place swap -> both results = partner half).  Here used ONLY
// with distinct registers (pk words).
__device__ __forceinline__ u32x2 plswap2(u32 a, u32 b) {
    return __builtin_amdgcn_permlane32_swap(a, b, false, false);
}

__device__ __forceinline__ void gload16(const void* g, void* l) {
    __builtin_amdgcn_global_load_lds(
        (const __attribute__((address_space(1))) unsigned*)g,
        (__attribute__((address_space(3))) unsigned*)l, 16, 0, 0);
}

// ---------------------------------------------------------------------------
__global__ __launch_bounds__(256) void cvt_x(const float* __restrict__ x,
                                             u16* __restrict__ xb) {
    const int i = (blockIdx.x * 256 + threadIdx.x) * 8;
    f32x4 a = *(const f32x4*)&x[i];
    f32x4 b = *(const f32x4*)&x[i + 4];
    u16 t[8];
#pragma unroll
    for (int j = 0; j < 4; ++j) { t[j] = f2bf(a[j]); t[4 + j] = f2bf(b[j]); }
    *(bf16x8*)&xb[i] = *(const bf16x8*)t;
}

// ---------------------------------------------------------------------------
__global__ __launch_bounds__(256) void cvt_w(const float* __restrict__ w0,
                                             const float* __restrict__ w1,
                                             const float* __restrict__ w2,
                                             const float* __restrict__ w3,
                                             u16* __restrict__ Wt) {
    __shared__ float T[64][65];
    const float* W = blockIdx.z == 0 ? w0 : blockIdx.z == 1 ? w1
                   : blockIdx.z == 2 ? w2 : w3;
    const int k0 = blockIdx.x * 64, n0 = blockIdx.y * 64;
    const int r  = threadIdx.x >> 2, c0 = (threadIdx.x & 3) * 16;
#pragma unroll
    for (int j = 0; j < 4; ++j)
        *(f32x4*)&T[r][c0 + j * 4] = *(const f32x4*)&W[(size_t)(k0 + r) * D_ + n0 + c0 + j * 4];
    __syncthreads();
    u16 tmp[16];
#pragma unroll
    for (int j = 0; j < 16; ++j) tmp[j] = f2bf(T[c0 + j][r]);
    u16* dst = Wt + ((size_t)blockIdx.z * 1024 + n0 + r) * K_ + k0 + c0;
    *(bf16x8*)dst       = *(const bf16x8*)tmp;
    *(bf16x8*)(dst + 8) = *(const bf16x8*)(tmp + 8);
}

// ---------------------------------------------------------------------------
// m97-style GEMM.  Biases passed directly; MODE 0 selects bq/bk/bv by n>>10
// (proven rounds 6-12).
// ---------------------------------------------------------------------------
template <int BM, int MODE>
__global__ __launch_bounds__(256) void gemm2(
    const u16* __restrict__ A, const u16* __restrict__ Bt,
    const float* __restrict__ b0, const float* __restrict__ b1,
    const float* __restrict__ b2, void* __restrict__ Out)
{
    __shared__ u16 As[BM * 32];
    __shared__ u16 Bs[128 * 32];
    const int tid = threadIdx.x, lane = tid & 63, wid = tid >> 6;
    const int lr = lane & 15, lg = lane >> 4;
    const int n0 = blockIdx.x * 128, m0 = blockIdx.y * BM;
    const int wm = (wid >> 1) * (BM / 2), wn = (wid & 1) * 64;
    const int lrow = lane >> 2, lch = lane & 3;

    f32x4 acc[BM / 32][4] = {};

    for (int k0 = 0; k0 < K_; k0 += 32) {
        __syncthreads();
#pragma unroll
        for (int t = 0; t < BM / 64; ++t) {
            const int row = wid * (BM / 4) + t * 16 + lrow;
            gload16(A + (size_t)(m0 + row) * K_ + k0 + lch * 8,
                    (u16*)As + row * 32 + lch * 8);
        }
#pragma unroll
        for (int t = 0; t < 2; ++t) {
            const int row = wid * 32 + t * 16 + lrow;
            gload16(Bt + (size_t)(n0 + row) * K_ + k0 + lch * 8,
                    (u16*)Bs + row * 32 + lch * 8);
        }
        __syncthreads();

        bf16x8 af[BM / 32], bf[4];
#pragma unroll
        for (int i = 0; i < BM / 32; ++i)
            af[i] = *(const bf16x8*)&As[(wm + i * 16 + lr) * 32 + lg * 8];
#pragma unroll
        for (int j = 0; j < 4; ++j)
            bf[j] = *(const bf16x8*)&Bs[(wn + j * 16 + lr) * 32 + lg * 8];
#pragma unroll
        for (int i = 0; i < BM / 32; ++i)
#pragma unroll
            for (int j = 0; j < 4; ++j) MFMA16(acc[i][j], af[i], bf[j]);
    }

#pragma unroll
    for (int i = 0; i < BM / 32; ++i) {
#pragma unroll
        for (int j = 0; j < 4; ++j) {
            const int n = n0 + wn + j * 16 + lr;
            const int m = m0 + wm + i * 16 + lg * 4;
            if constexpr (MODE == 0) {
                const int which = n >> 10, nn = n & 1023;
                const float* bp = which == 0 ? b0 : which == 1 ? b1 : b2;
                const float bv = bp[nn];
                u16* qkv = (u16*)Out;
                const int h = nn >> 6, hd = nn & 63;
                const int b = m >> 11, s = m & 2047;
                if (which == 2) {                         // V: [bh][hd][s]
                    u16x4 pk;
#pragma unroll
                    for (int r4 = 0; r4 < 4; ++r4) pk[r4] = f2bf(acc[i][j][r4] + bv);
                    *(u16x4*)&qkv[(size_t)2 * NEL +
                                  ((size_t)(b * H_ + h) * HD_ + hd) * S_ + s] = pk;
                } else {                                  // Q/K: [bh][s][hd]
                    const float sc = (which == 0) ? QSCALE : 1.0f;
                    const size_t bas = (size_t)which * NEL + (size_t)(b * H_ + h) * S_ * HD_;
#pragma unroll
                    for (int r4 = 0; r4 < 4; ++r4)
                        qkv[bas + (size_t)(s + r4) * HD_ + hd] =
                            f2bf((acc[i][j][r4] + bv) * sc);
                }
            } else {
                const float bv = b0[n];
                float* o = (float*)Out;
#pragma unroll
                for (int r4 = 0; r4 < 4; ++r4)
                    o[(size_t)(m + r4) * D_ + n] = acc[i][j][r4] + bv;
            }
        }
    }
}

// ---------------------------------------------------------------------------
// attn10: round-12 attn5 (proven 73us) with ONE change: PV A-frag exchange
// via permlane32_swap on DISTINCT registers (pk[w] vs pk[w+2]) instead of
// 8 ds_bpermute + 48 v_cndmask.  Reductions keep proven __shfl_xor.
// Runtime orientation probe (wave-uniform flip) covers return-order
// ambiguity of the builtin's {vdst', vsrc'} pair.
// Round-11 failure root-cause: plswap2(u,u) operand aliasing in the
// REDUCTIONS (in-place swap -> partner-max instead of row-max) — the
// A-frag swap itself was derivation-verified correct.
// C/D layout: col=lane&31, row=(r&3)+8(r>>2)+4*(lane>>5)  [m74/m101].
// ---------------------------------------------------------------------------
__global__ __launch_bounds__(128) void attn10(
    const u16* __restrict__ Q, const u16* __restrict__ K,
    const u16* __restrict__ Vt, u16* __restrict__ CTX)
{
    __shared__ float OB[64][33];   // wave1 partial O (r-space), pad -> conflict-free
    __shared__ float MB[64], LB[64];

    const int tid  = threadIdx.x;
    const int lane = tid & 63, wv = tid >> 6;
    const int lo = lane & 31, hi = lane >> 5;
    const int idx = blockIdx.x;
    const int bh  = idx & 31;
    const int qb  = 63 - (idx >> 5);       // heavy q-blocks first
    const int wq0 = qb * 32;
    const size_t base  = (size_t)bh * S_ * HD_;   // Q,K: [bh][s][hd]
    const size_t vbase = (size_t)bh * HD_ * S_;   // Vt:  [bh][hd][s]

    // ---- permlane return-order probe (wave-uniform) ----
    // vdst=pa rows {20|10}, vsrc=pb rows {40|30}.  Doc order {vdst',vsrc'}:
    // pr[0] = hi? 40:20.  Flipped order {vsrc',vdst'}: pr[0] = hi? 30:10.
    bool flip;
    {
        u32 pa = hi ? 10u : 20u;
        u32 pb = hi ? 30u : 40u;
        u32x2 pr = plswap2(pa, pb);
        flip = (pr[0] == 10u) || (pr[0] == 30u);
    }

    // Q as B-fragment: lane holds col q=lo, k = 16*ks + 8*hi + j
    bf16x8 qf[4];
#pragma unroll
    for (int ks = 0; ks < 4; ++ks)
        qf[ks] = *(const bf16x8*)&Q[base + (size_t)(wq0 + lo) * HD_ + ks * 16 + hi * 8];

    f32x16 acc[2] = {};
    float m_ = -1e30f, l_ = 0.f;
    const int nt = (wq0 >> 6) + 1;

    for (int t = wv; t < nt; t += 2) {
        const int kv0 = t * 64;
        const bool sub1 = (kv0 + 32 <= wq0 + 31);

        // ---- QK^T (S^T): A = K rows, B = Q ----
        f32x16 cT[2];
#pragma unroll
        for (int i = 0; i < 16; ++i) { cT[0][i] = 0.f; cT[1][i] = 0.f; }
        __builtin_amdgcn_s_setprio(1);
#pragma unroll
        for (int ks = 0; ks < 4; ++ks) {
            bf16x8 kf = *(const bf16x8*)&K[base + (size_t)(kv0 + lo) * HD_ + ks * 16 + hi * 8];
            MFMA32(cT[0], kf, qf[ks]);
        }
        if (sub1) {
#pragma unroll
            for (int ks = 0; ks < 4; ++ks) {
                bf16x8 kf = *(const bf16x8*)&K[base + (size_t)(kv0 + 32 + lo) * HD_ + ks * 16 + hi * 8];
                MFMA32(cT[1], kf, qf[ks]);
            }
        }
        __builtin_amdgcn_s_setprio(0);

        // ---- V B-frags issued early (hide under softmax) ----
        bf16x8 vf[2][4];
#pragma unroll
        for (int dt = 0; dt < 2; ++dt)
#pragma unroll
            for (int ks = 0; ks < 4; ++ks)
                if (ks < 2 || sub1)
                    vf[dt][ks] = *(const bf16x8*)&Vt[vbase + (size_t)(dt * 32 + lo) * S_ +
                                                     kv0 + ks * 16 + hi * 8];

        // ---- causal mask (diagonal passes only) ----
        if (kv0 + 63 > wq0) {
            const int qg = wq0 + lo;
#pragma unroll
            for (int tt = 0; tt < 2; ++tt)
#pragma unroll
                for (int r = 0; r < 16; ++r) {
                    const int kvg = kv0 + tt * 32 + (r & 3) + 8 * (r >> 2) + 4 * hi;
                    if (kvg > qg) cT[tt][r] = -1e9f;
                }
        }

        // ---- row max: in-register tree + 1 cross-lane (proven shfl) ----
        float m8[8];
#pragma unroll
        for (int i = 0; i < 8; ++i)
            m8[i] = fmaxf(fmaxf(cT[0][i], cT[0][i + 8]), fmaxf(cT[1][i], cT[1][i + 8]));
        float mx = fmaxf(fmaxf(fmaxf(m8[0], m8[1]), fmaxf(m8[2], m8[3])),
                         fmaxf(fmaxf(m8[4], m8[5]), fmaxf(m8[6], m8[7])));
        mx = fmaxf(mx, __shfl_xor(mx, 32));

        // ---- defer-max (T13, exp2 domain: 11.5 = 8*log2e) ----
        if (!__all(mx <= m_ + 11.5f)) {
            const float mn = fmaxf(m_, mx);
            const float al = exp2f(m_ - mn);
            m_ = mn; l_ *= al;
            float alr[16];
#pragma unroll
            for (int r = 0; r < 16; ++r)
                alr[r] = __shfl(al, (r & 3) + 8 * (r >> 2) + 4 * hi);
#pragma unroll
            for (int r = 0; r < 16; ++r) { acc[0][r] *= alr[r]; acc[1][r] *= alr[r]; }
        }

        // ---- P = exp2(S - m), lane-local sum + 1 cross-lane ----
#pragma unroll
        for (int i = 0; i < 16; ++i) {
            cT[0][i] = exp2f(cT[0][i] - m_);
            cT[1][i] = exp2f(cT[1][i] - m_);
        }
        float s8[8];
#pragma unroll
        for (int i = 0; i < 8; ++i)
            s8[i] = (cT[0][i] + cT[0][i + 8]) + (cT[1][i] + cT[1][i + 8]);
        float ssum = ((s8[0] + s8[1]) + (s8[2] + s8[3])) +
                     ((s8[4] + s8[5]) + (s8[6] + s8[7]));
        ssum += __shfl_xor(ssum, 32);
        l_ += ssum;

        // ---- pack P to bf16 pairs ----
        u32 pk[2][8];
#pragma unroll
        for (int tt = 0; tt < 2; ++tt)
#pragma unroll
            for (int w = 0; w < 8; ++w)
                pk[tt][w] = cvtpk(cT[tt][2 * w], cT[tt][2 * w + 1]);

        // ---- build PV A-frags via permlane32_swap (distinct regs); PV ----
        // Derivation (matches verified round-5 routing):
        //   s0 = swap(pk[o4], pk[o4+2]):  vdst' = own(lo-half)|partner,
        //   vsrc' = partner|own(hi-half)  ->  af.x = s0[0], af.z = s0[1].
#pragma unroll
        for (int ks = 0; ks < 4; ++ks) {
            if (ks < 2 || sub1) {
                const int tt = ks >> 1;
                const int o4 = (ks & 1) * 4;
                u32x2 s0 = plswap2(pk[tt][o4 + 0], pk[tt][o4 + 2]);
                u32x2 s1 = plswap2(pk[tt][o4 + 1], pk[tt][o4 + 3]);
                u32x4v v;
                v.x = flip ? s0[1] : s0[0];
                v.y = flip ? s1[1] : s1[0];
                v.z = flip ? s0[0] : s0[1];
                v.w = flip ? s1[0] : s1[1];
                const bf16x8 af = __builtin_bit_cast(bf16x8, v);
                __builtin_amdgcn_s_setprio(1);
                MFMA32(acc[0], af, vf[0][ks]);
                MFMA32(acc[1], af, vf[1][ks]);
                __builtin_amdgcn_s_setprio(0);
            }
        }
    }

    // ---- in-block merge: wave1 publishes, wave0 combines + stores ----
    if (wv == 1) {
#pragma unroll
        for (int r = 0; r < 16; ++r) {
            OB[lane][r]      = acc[0][r];
            OB[lane][16 + r] = acc[1][r];
        }
        MB[lane] = m_;
        LB[lane] = l_;
    }
    __syncthreads();
    if (wv != 0) return;

    const float m1 = MB[lane], l1 = LB[lane];
    const float mM = fmaxf(m_, m1);
    const float a0 = exp2f(m_ - mM), a1 = exp2f(m1 - mM);
    l_ = l_ * a0 + l1 * a1;
    float a0r[16], a1r[16];
#pragma unroll
    for (int r = 0; r < 16; ++r) {
        const int rq = (r & 3) + 8 * (r >> 2) + 4 * hi;
        a0r[r] = __shfl(a0, rq);
        a1r[r] = __shfl(a1, rq);
    }
#pragma unroll
    for (int r = 0; r < 16; ++r) {
        acc[0][r] = acc[0][r] * a0r[r] + OB[lane][r]      * a1r[r];
        acc[1][r] = acc[1][r] * a0r[r] + OB[lane][16 + r] * a1r[r];
    }

    const float linv = 1.0f / l_;
    float lrr[16];
#pragma unroll
    for (int r = 0; r < 16; ++r)
        lrr[r] = __shfl(linv, (r & 3) + 8 * (r >> 2) + 4 * hi);
    const int b = bh >> 4, h = bh & 15;
#pragma unroll
    for (int r = 0; r < 16; ++r) {
        const int q = wq0 + (r & 3) + 8 * (r >> 2) + 4 * hi;
        u16* o = &CTX[(size_t)(b * S_ + q) * D_ + h * HD_ + lo];
        o[0]  = f2bf(acc[0][r] * lrr[r]);
        o[32] = f2bf(acc[1][r] * lrr[r]);
    }
}

// ---------------------------------------------------------------------------
extern "C" void kernel_launch(void* const* d_in, const int* in_sizes, int n_in,
                              void* d_out, int out_size, void* d_ws, size_t ws_size,
                              hipStream_t stream)
{
    const float* x  = (const float*)d_in[0];
    const float* wq = (const float*)d_in[1];
    const float* bq = (const float*)d_in[2];
    const float* wk = (const float*)d_in[3];
    const float* bk = (const float*)d_in[4];
    const float* wv = (const float*)d_in[5];
    const float* bv = (const float*)d_in[6];
    const float* wo = (const float*)d_in[7];
    const float* bo = (const float*)d_in[8];

    char* ws = (char*)d_ws;
    u16*   xb    = (u16*)ws;                                  // 8 MB (reused as ctx)
    u16*   WtAll = (u16*)(ws + (size_t)8  * 1024 * 1024);     // 8 MB, rows q|k|v|o
    u16*   qkv   = (u16*)(ws + (size_t)16 * 1024 * 1024);     // 24 MB: q | k | vT
    u16*   ctx   = xb;

    cvt_x<<<2048, 256, 0, stream>>>(x, xb);
    cvt_w<<<dim3(16, 16, 4), 256, 0, stream>>>(wq, wk, wv, wo, WtAll);

    gemm2<128, 0><<<dim3(24, 32), 256, 0, stream>>>(xb, WtAll, bq, bk, bv, qkv);

    attn10<<<dim3(2048), 128, 0, stream>>>(qkv, qkv + NEL, qkv + 2 * (size_t)NEL, ctx);

    gemm2<64, 1><<<dim3(8, 64), 256, 0, stream>>>(ctx, WtAll + (size_t)3072 * K_,
                                                  bo, bo, bo, d_out);
}

// Round 14
// 134.684 us; speedup vs baseline: 1.2818x; 1.1088x over previous
//
#include <hip/hip_runtime.h>

#define S_  2048
#define D_  1024
#define H_  16
#define HD_ 64
#define M_  4096
#define K_  1024
#define NEL 4194304   // B*H*S*HD

typedef short  bf16x8 __attribute__((ext_vector_type(8)));
typedef float  f32x4  __attribute__((ext_vector_type(4)));
typedef float  f32x16 __attribute__((ext_vector_type(16)));
typedef unsigned int   u32;
typedef unsigned int   u32x2 __attribute__((ext_vector_type(2)));
typedef unsigned int   u32x4v __attribute__((ext_vector_type(4)));
typedef unsigned short u16;
typedef unsigned short u16x4 __attribute__((ext_vector_type(4)));

#define MFMA16(c,a,b) (c) = __builtin_amdgcn_mfma_f32_16x16x32_bf16((a),(b),(c),0,0,0)
#define MFMA32(c,a,b) (c) = __builtin_amdgcn_mfma_f32_32x32x16_bf16((a),(b),(c),0,0,0)

// Q pre-scale: 1/sqrt(64) * log2(e) -> softmax in exp2 domain
#define QSCALE 0.18033688011112042f

__device__ __forceinline__ u16 f2bf(float f) {
    union { float f; unsigned u; } v; v.f = f;
    unsigned u = v.u;
    u += 0x7FFFu + ((u >> 16) & 1u);   // RNE
    return (u16)(u >> 16);
}

__device__ __forceinline__ u32 cvtpk(float lo, float hi) {
    u32 r;
    asm("v_cvt_pk_bf16_f32 %0, %1, %2" : "=v"(r) : "v"(lo), "v"(hi));
    return r;
}

// permlane32_swap on DISTINCT registers only (round-11 lesson: aliased
// operands coalesce -> in-place swap -> garbage).  Proven in round 13.
__device__ __forceinline__ u32x2 plswap2(u32 a, u32 b) {
    return __builtin_amdgcn_permlane32_swap(a, b, false, false);
}

__device__ __forceinline__ void gload16(const void* g, void* l) {
    __builtin_amdgcn_global_load_lds(
        (const __attribute__((address_space(1))) unsigned*)g,
        (__attribute__((address_space(3))) unsigned*)l, 16, 0, 0);
}

// ---------------------------------------------------------------------------
__global__ __launch_bounds__(256) void cvt_x(const float* __restrict__ x,
                                             u16* __restrict__ xb) {
    const int i = (blockIdx.x * 256 + threadIdx.x) * 8;
    f32x4 a = *(const f32x4*)&x[i];
    f32x4 b = *(const f32x4*)&x[i + 4];
    u16 t[8];
#pragma unroll
    for (int j = 0; j < 4; ++j) { t[j] = f2bf(a[j]); t[4 + j] = f2bf(b[j]); }
    *(bf16x8*)&xb[i] = *(const bf16x8*)t;
}

// ---------------------------------------------------------------------------
__global__ __launch_bounds__(256) void cvt_w(const float* __restrict__ w0,
                                             const float* __restrict__ w1,
                                             const float* __restrict__ w2,
                                             const float* __restrict__ w3,
                                             u16* __restrict__ Wt) {
    __shared__ float T[64][65];
    const float* W = blockIdx.z == 0 ? w0 : blockIdx.z == 1 ? w1
                   : blockIdx.z == 2 ? w2 : w3;
    const int k0 = blockIdx.x * 64, n0 = blockIdx.y * 64;
    const int r  = threadIdx.x >> 2, c0 = (threadIdx.x & 3) * 16;
#pragma unroll
    for (int j = 0; j < 4; ++j)
        *(f32x4*)&T[r][c0 + j * 4] = *(const f32x4*)&W[(size_t)(k0 + r) * D_ + n0 + c0 + j * 4];
    __syncthreads();
    u16 tmp[16];
#pragma unroll
    for (int j = 0; j < 16; ++j) tmp[j] = f2bf(T[c0 + j][r]);
    u16* dst = Wt + ((size_t)blockIdx.z * 1024 + n0 + r) * K_ + k0 + c0;
    *(bf16x8*)dst       = *(const bf16x8*)tmp;
    *(bf16x8*)(dst + 8) = *(const bf16x8*)(tmp + 8);
}

// ---------------------------------------------------------------------------
// m97-style GEMM.  Biases passed directly; MODE 0 selects bq/bk/bv by n>>10
// (proven rounds 6-13).
// ---------------------------------------------------------------------------
template <int BM, int MODE>
__global__ __launch_bounds__(256) void gemm2(
    const u16* __restrict__ A, const u16* __restrict__ Bt,
    const float* __restrict__ b0, const float* __restrict__ b1,
    const float* __restrict__ b2, void* __restrict__ Out)
{
    __shared__ u16 As[BM * 32];
    __shared__ u16 Bs[128 * 32];
    const int tid = threadIdx.x, lane = tid & 63, wid = tid >> 6;
    const int lr = lane & 15, lg = lane >> 4;
    const int n0 = blockIdx.x * 128, m0 = blockIdx.y * BM;
    const int wm = (wid >> 1) * (BM / 2), wn = (wid & 1) * 64;
    const int lrow = lane >> 2, lch = lane & 3;

    f32x4 acc[BM / 32][4] = {};

    for (int k0 = 0; k0 < K_; k0 += 32) {
        __syncthreads();
#pragma unroll
        for (int t = 0; t < BM / 64; ++t) {
            const int row = wid * (BM / 4) + t * 16 + lrow;
            gload16(A + (size_t)(m0 + row) * K_ + k0 + lch * 8,
                    (u16*)As + row * 32 + lch * 8);
        }
#pragma unroll
        for (int t = 0; t < 2; ++t) {
            const int row = wid * 32 + t * 16 + lrow;
            gload16(Bt + (size_t)(n0 + row) * K_ + k0 + lch * 8,
                    (u16*)Bs + row * 32 + lch * 8);
        }
        __syncthreads();

        bf16x8 af[BM / 32], bf[4];
#pragma unroll
        for (int i = 0; i < BM / 32; ++i)
            af[i] = *(const bf16x8*)&As[(wm + i * 16 + lr) * 32 + lg * 8];
#pragma unroll
        for (int j = 0; j < 4; ++j)
            bf[j] = *(const bf16x8*)&Bs[(wn + j * 16 + lr) * 32 + lg * 8];
#pragma unroll
        for (int i = 0; i < BM / 32; ++i)
#pragma unroll
            for (int j = 0; j < 4; ++j) MFMA16(acc[i][j], af[i], bf[j]);
    }

#pragma unroll
    for (int i = 0; i < BM / 32; ++i) {
#pragma unroll
        for (int j = 0; j < 4; ++j) {
            const int n = n0 + wn + j * 16 + lr;
            const int m = m0 + wm + i * 16 + lg * 4;
            if constexpr (MODE == 0) {
                const int which = n >> 10, nn = n & 1023;
                const float* bp = which == 0 ? b0 : which == 1 ? b1 : b2;
                const float bv = bp[nn];
                u16* qkv = (u16*)Out;
                const int h = nn >> 6, hd = nn & 63;
                const int b = m >> 11, s = m & 2047;
                if (which == 2) {                         // V: [bh][hd][s]
                    u16x4 pk;
#pragma unroll
                    for (int r4 = 0; r4 < 4; ++r4) pk[r4] = f2bf(acc[i][j][r4] + bv);
                    *(u16x4*)&qkv[(size_t)2 * NEL +
                                  ((size_t)(b * H_ + h) * HD_ + hd) * S_ + s] = pk;
                } else {                                  // Q/K: [bh][s][hd]
                    const float sc = (which == 0) ? QSCALE : 1.0f;
                    const size_t bas = (size_t)which * NEL + (size_t)(b * H_ + h) * S_ * HD_;
#pragma unroll
                    for (int r4 = 0; r4 < 4; ++r4)
                        qkv[bas + (size_t)(s + r4) * HD_ + hd] =
                            f2bf((acc[i][j][r4] + bv) * sc);
                }
            } else {
                const float bv = b0[n];
                float* o = (float*)Out;
#pragma unroll
                for (int r4 = 0; r4 < 4; ++r4)
                    o[(size_t)(m + r4) * D_ + n] = acc[i][j][r4] + bv;
            }
        }
    }
}

// ---------------------------------------------------------------------------
// attn11: round-13 datapath + per-wave LDS staging of K/V tiles.
// THEORY: direct fragment loads are 32-cacheline gathers (rows 128B apart);
// 16/pass with L1 thrash => ~512 L2 line-requests/pass => L2 request-rate
// bound (explains flat ~72us across occupancy/VALU changes, rounds 5-13).
// FIX: coalesced global_load_lds staging (8 lines/instr, 16 instr/pass =
// 128 requests, 4x less), fragments via swizzled ds_read_b128.
// Swizzle (m173 pattern): LDS linear dest; global source chunk ^= row&7;
// reader chunk c -> c^(row&7).  Per-wave private => NO barriers, vmcnt only.
// Merge buffers alias wave-1's staging region (dead after its loop).
// C/D layout: col=lane&31, row=(r&3)+8(r>>2)+4*(lane>>5)  [m74/m101].
// ---------------------------------------------------------------------------
__global__ __launch_bounds__(128) void attn11(
    const u16* __restrict__ Q, const u16* __restrict__ K,
    const u16* __restrict__ Vt, u16* __restrict__ CTX)
{
    __shared__ __align__(16) char SMEM[32768];   // [wave][K 8KB | V 8KB]

    const int tid  = threadIdx.x;
    const int lane = tid & 63, wv = tid >> 6;
    const int lo = lane & 31, hi = lane >> 5;
    const int idx = blockIdx.x;
    const int bh  = idx & 31;
    const int qb  = 63 - (idx >> 5);       // heavy q-blocks first
    const int wq0 = qb * 32;
    const size_t base  = (size_t)bh * S_ * HD_;   // Q,K: [bh][s][hd]
    const size_t vbase = (size_t)bh * HD_ * S_;   // Vt:  [bh][hd][s]

    char* Kw = SMEM + wv * 16384;
    char* Vw = Kw + 8192;
    // merge buffers alias wave-1's staging region (written only post-loop)
    float (*OB)[33] = (float (*)[33])(SMEM + 16384);
    float* MBp = (float*)(SMEM + 16384 + 8448);
    float* LBp = MBp + 64;

    // permlane return-order probe (wave-uniform)
    bool flip;
    {
        u32 pa = hi ? 10u : 20u;
        u32 pb = hi ? 30u : 40u;
        u32x2 pr = plswap2(pa, pb);
        flip = (pr[0] == 10u) || (pr[0] == 30u);
    }

    // staging lane decomposition: 8 lanes/row, 16B chunks, swizzled source
    const int r8  = lane >> 3;            // row within 8-row group (= row&7)
    const int csw = (lane & 7) ^ r8;      // source chunk (XOR swizzle)
    const int swz = lo & 7;               // reader swizzle key

    // Q as B-fragment: lane holds col q=lo, k = 16*ks + 8*hi + j
    bf16x8 qf[4];
#pragma unroll
    for (int ks = 0; ks < 4; ++ks)
        qf[ks] = *(const bf16x8*)&Q[base + (size_t)(wq0 + lo) * HD_ + ks * 16 + hi * 8];

    f32x16 acc[2] = {};
    float m_ = -1e30f, l_ = 0.f;
    const int nt = (wq0 >> 6) + 1;

    for (int t = wv; t < nt; t += 2) {
        const int kv0 = t * 64;
        const bool sub1 = (kv0 + 32 <= wq0 + 31);

        // ---- stage K (64 or 32 rows x 128B) + V (64 rows x 128B) ----
        {
            const u16* kSrc = K  + base  + (size_t)(kv0 + r8) * HD_ + csw * 8;
            const u16* vSrc = Vt + vbase + (size_t)r8 * S_ + kv0 + csw * 8;
            char* kDst = Kw + (lane << 4);
            char* vDst = Vw + (lane << 4);
            const int ni = sub1 ? 8 : 4;
            for (int i = 0; i < ni; ++i)
                gload16(kSrc + (size_t)(i * 8) * HD_, kDst + i * 1024);
#pragma unroll
            for (int i = 0; i < 8; ++i)
                gload16(vSrc + (size_t)(i * 8) * S_, vDst + i * 1024);
            asm volatile("s_waitcnt vmcnt(0)" ::: "memory");
        }

        // ---- QK^T (S^T): A = K rows (from LDS), B = Q ----
        f32x16 cT[2];
#pragma unroll
        for (int i = 0; i < 16; ++i) { cT[0][i] = 0.f; cT[1][i] = 0.f; }
        __builtin_amdgcn_s_setprio(1);
#pragma unroll
        for (int ks = 0; ks < 4; ++ks) {
            bf16x8 kf = *(const bf16x8*)(Kw + (lo << 7) + (((2 * ks + hi) ^ swz) << 4));
            MFMA32(cT[0], kf, qf[ks]);
        }
        if (sub1) {
#pragma unroll
            for (int ks = 0; ks < 4; ++ks) {
                bf16x8 kf = *(const bf16x8*)(Kw + ((32 + lo) << 7) + (((2 * ks + hi) ^ swz) << 4));
                MFMA32(cT[1], kf, qf[ks]);
            }
        }
        __builtin_amdgcn_s_setprio(0);

        // ---- V B-frags read early from LDS (hide under softmax) ----
        bf16x8 vf[2][4];
#pragma unroll
        for (int dt = 0; dt < 2; ++dt)
#pragma unroll
            for (int ks = 0; ks < 4; ++ks)
                if (ks < 2 || sub1)
                    vf[dt][ks] = *(const bf16x8*)(Vw + ((dt * 32 + lo) << 7) +
                                                  (((2 * ks + hi) ^ swz) << 4));

        // ---- causal mask (diagonal passes only) ----
        if (kv0 + 63 > wq0) {
            const int qg = wq0 + lo;
#pragma unroll
            for (int tt = 0; tt < 2; ++tt)
#pragma unroll
                for (int r = 0; r < 16; ++r) {
                    const int kvg = kv0 + tt * 32 + (r & 3) + 8 * (r >> 2) + 4 * hi;
                    if (kvg > qg) cT[tt][r] = -1e9f;
                }
        }

        // ---- row max: in-register tree + 1 cross-lane (proven shfl) ----
        float m8[8];
#pragma unroll
        for (int i = 0; i < 8; ++i)
            m8[i] = fmaxf(fmaxf(cT[0][i], cT[0][i + 8]), fmaxf(cT[1][i], cT[1][i + 8]));
        float mx = fmaxf(fmaxf(fmaxf(m8[0], m8[1]), fmaxf(m8[2], m8[3])),
                         fmaxf(fmaxf(m8[4], m8[5]), fmaxf(m8[6], m8[7])));
        mx = fmaxf(mx, __shfl_xor(mx, 32));

        // ---- defer-max (T13, exp2 domain: 11.5 = 8*log2e) ----
        if (!__all(mx <= m_ + 11.5f)) {
            const float mn = fmaxf(m_, mx);
            const float al = exp2f(m_ - mn);
            m_ = mn; l_ *= al;
            float alr[16];
#pragma unroll
            for (int r = 0; r < 16; ++r)
                alr[r] = __shfl(al, (r & 3) + 8 * (r >> 2) + 4 * hi);
#pragma unroll
            for (int r = 0; r < 16; ++r) { acc[0][r] *= alr[r]; acc[1][r] *= alr[r]; }
        }

        // ---- P = exp2(S - m), lane-local sum + 1 cross-lane ----
#pragma unroll
        for (int i = 0; i < 16; ++i) {
            cT[0][i] = exp2f(cT[0][i] - m_);
            cT[1][i] = exp2f(cT[1][i] - m_);
        }
        float s8[8];
#pragma unroll
        for (int i = 0; i < 8; ++i)
            s8[i] = (cT[0][i] + cT[0][i + 8]) + (cT[1][i] + cT[1][i + 8]);
        float ssum = ((s8[0] + s8[1]) + (s8[2] + s8[3])) +
                     ((s8[4] + s8[5]) + (s8[6] + s8[7]));
        ssum += __shfl_xor(ssum, 32);
        l_ += ssum;

        // ---- pack P to bf16 pairs ----
        u32 pk[2][8];
#pragma unroll
        for (int tt = 0; tt < 2; ++tt)
#pragma unroll
            for (int w = 0; w < 8; ++w)
                pk[tt][w] = cvtpk(cT[tt][2 * w], cT[tt][2 * w + 1]);

        // ---- build PV A-frags via permlane32_swap (proven r13); PV ----
#pragma unroll
        for (int ks = 0; ks < 4; ++ks) {
            if (ks < 2 || sub1) {
                const int tt = ks >> 1;
                const int o4 = (ks & 1) * 4;
                u32x2 s0 = plswap2(pk[tt][o4 + 0], pk[tt][o4 + 2]);
                u32x2 s1 = plswap2(pk[tt][o4 + 1], pk[tt][o4 + 3]);
                u32x4v v;
                v.x = flip ? s0[1] : s0[0];
                v.y = flip ? s1[1] : s1[0];
                v.z = flip ? s0[0] : s0[1];
                v.w = flip ? s1[0] : s1[1];
                const bf16x8 af = __builtin_bit_cast(bf16x8, v);
                __builtin_amdgcn_s_setprio(1);
                MFMA32(acc[0], af, vf[0][ks]);
                MFMA32(acc[1], af, vf[1][ks]);
                __builtin_amdgcn_s_setprio(0);
            }
        }
    }

    // ---- in-block merge: wave1 publishes (into its own dead LDS), wave0
    //      combines + stores ----
    if (wv == 1) {
#pragma unroll
        for (int r = 0; r < 16; ++r) {
            OB[lane][r]      = acc[0][r];
            OB[lane][16 + r] = acc[1][r];
        }
        MBp[lane] = m_;
        LBp[lane] = l_;
    }
    __syncthreads();
    if (wv != 0) return;

    const float m1 = MBp[lane], l1 = LBp[lane];
    const float mM = fmaxf(m_, m1);
    const float a0 = exp2f(m_ - mM), a1 = exp2f(m1 - mM);
    l_ = l_ * a0 + l1 * a1;
    float a0r[16], a1r[16];
#pragma unroll
    for (int r = 0; r < 16; ++r) {
        const int rq = (r & 3) + 8 * (r >> 2) + 4 * hi;
        a0r[r] = __shfl(a0, rq);
        a1r[r] = __shfl(a1, rq);
    }
#pragma unroll
    for (int r = 0; r < 16; ++r) {
        acc[0][r] = acc[0][r] * a0r[r] + OB[lane][r]      * a1r[r];
        acc[1][r] = acc[1][r] * a0r[r] + OB[lane][16 + r] * a1r[r];
    }

    const float linv = 1.0f / l_;
    float lrr[16];
#pragma unroll
    for (int r = 0; r < 16; ++r)
        lrr[r] = __shfl(linv, (r & 3) + 8 * (r >> 2) + 4 * hi);
    const int b = bh >> 4, h = bh & 15;
#pragma unroll
    for (int r = 0; r < 16; ++r) {
        const int q = wq0 + (r & 3) + 8 * (r >> 2) + 4 * hi;
        u16* o = &CTX[(size_t)(b * S_ + q) * D_ + h * HD_ + lo];
        o[0]  = f2bf(acc[0][r] * lrr[r]);
        o[32] = f2bf(acc[1][r] * lrr[r]);
    }
}

// ---------------------------------------------------------------------------
extern "C" void kernel_launch(void* const* d_in, const int* in_sizes, int n_in,
                              void* d_out, int out_size, void* d_ws, size_t ws_size,
                              hipStream_t stream)
{
    const float* x  = (const float*)d_in[0];
    const float* wq = (const float*)d_in[1];
    const float* bq = (const float*)d_in[2];
    const float* wk = (const float*)d_in[3];
    const float* bk = (const float*)d_in[4];
    const float* wv = (const float*)d_in[5];
    const float* bv = (const float*)d_in[6];
    const float* wo = (const float*)d_in[7];
    const float* bo = (const float*)d_in[8];

    char* ws = (char*)d_ws;
    u16*   xb    = (u16*)ws;                                  // 8 MB (reused as ctx)
    u16*   WtAll = (u16*)(ws + (size_t)8  * 1024 * 1024);     // 8 MB, rows q|k|v|o
    u16*   qkv   = (u16*)(ws + (size_t)16 * 1024 * 1024);     // 24 MB: q | k | vT
    u16*   ctx   = xb;

    cvt_x<<<2048, 256, 0, stream>>>(x, xb);
    cvt_w<<<dim3(16, 16, 4), 256, 0, stream>>>(wq, wk, wv, wo, WtAll);

    gemm2<128, 0><<<dim3(24, 32), 256, 0, stream>>>(xb, WtAll, bq, bk, bv, qkv);

    attn11<<<dim3(2048), 128, 0, stream>>>(qkv, qkv + NEL, qkv + 2 * (size_t)NEL, ctx);

    gemm2<64, 1><<<dim3(8, 64), 256, 0, stream>>>(ctx, WtAll + (size_t)3072 * K_,
                                                  bo, bo, bo, d_out);
}